// Round 13
// baseline (203.366 us; speedup 1.0000x reference)
//
#include <hip/hip_runtime.h>
#include <cstdint>
#include <cstddef>

// Problem constants
#define BB 2
#define TT 2048
#define DMODEL 1024
#define NHEADS 16
#define DK 64

typedef short short8 __attribute__((ext_vector_type(8)));
typedef unsigned short ushort8 __attribute__((ext_vector_type(8)));
typedef float floatx4 __attribute__((ext_vector_type(4)));
typedef _Float16 half4 __attribute__((ext_vector_type(4)));

// gfx950 f16 MFMA 16x16x16: A/B = 4xf16 (2 VGPR), C/D = 4xf32
#define MFMA_PV(A, B, C) __builtin_amdgcn_mfma_f32_16x16x16f16(A, B, C, 0, 0, 0)

// ---------- helpers ----------
__device__ __forceinline__ unsigned short f2bf(float f) {
    uint32_t u = __builtin_bit_cast(uint32_t, f);
    uint32_t r = (u + 0x7FFFu + ((u >> 16) & 1u)) >> 16;
    return (unsigned short)r;
}
__device__ __forceinline__ float bf2f(unsigned short s) {
    uint32_t u = ((uint32_t)s) << 16;
    return __builtin_bit_cast(float, u);
}

#define GLDS16(g, l) __builtin_amdgcn_global_load_lds( \
    (const __attribute__((address_space(1))) void*)(g), \
    (__attribute__((address_space(3))) void*)(l), 16, 0, 0)

// ---------- merged cast fp32 -> bf16 for x, w_qkv, w_out (one launch) ----------
__global__ void castk3(const float* __restrict__ x, unsigned short* __restrict__ xb,
                       const float* __restrict__ wq, unsigned short* __restrict__ wqb,
                       const float* __restrict__ wo, unsigned short* __restrict__ wob) {
    int bid = blockIdx.x;
    const float* in;
    unsigned short* out;
    int base;
    if (bid < 4096)       { in = x;  out = xb;  base = bid * 1024; }
    else if (bid < 7168)  { in = wq; out = wqb; base = (bid - 4096) * 1024; }
    else                  { in = wo; out = wob; base = (bid - 7168) * 1024; }
    int i = base + threadIdx.x * 4;
    float4 v = *(const float4*)(in + i);
    ushort4 o;
    o.x = f2bf(v.x); o.y = f2bf(v.y); o.z = f2bf(v.z); o.w = f2bf(v.w);
    *(ushort4*)(out + i) = o;
}

// ---------- bf16 MFMA GEMM, C = A * B^T, BK=32 (R10-proven: 0 conflicts) ----------
// A: [M][K], B: [N][K]. OUT = float (fp32 C) or unsigned short (bf16 C).
template <typename OUT>
__global__ __launch_bounds__(256)
void gemm_bt(const unsigned short* __restrict__ A, const unsigned short* __restrict__ B,
             OUT* __restrict__ C, int M, int N, int K) {
    __shared__ unsigned short As[128 * 32];
    __shared__ unsigned short Bs[128 * 32];

    const int tid  = threadIdx.x;
    const int lane = tid & 63;
    const int w    = tid >> 6;
    const int wm   = w & 1;
    const int wn   = w >> 1;
    const int quad = lane >> 4;
    const int l16  = lane & 15;

    const int m0 = blockIdx.y * 128;
    const int n0 = blockIdx.x * 128;

    floatx4 acc[4][4];
#pragma unroll
    for (int a = 0; a < 4; a++)
#pragma unroll
        for (int b = 0; b < 4; b++)
            acc[a][b] = (floatx4){0.f, 0.f, 0.f, 0.f};

    const int c0 = w * 128 + lane;
    const int c1 = c0 + 64;
    const int r0 = c0 >> 2, cc0 = (c0 & 3) ^ ((r0 >> 1) & 3);
    const int r1 = c1 >> 2, cc1 = (c1 & 3) ^ ((r1 >> 1) & 3);

    const unsigned short* gA0 = A + (size_t)(m0 + r0) * K + cc0 * 8;
    const unsigned short* gA1 = A + (size_t)(m0 + r1) * K + cc1 * 8;
    const unsigned short* gB0 = B + (size_t)(n0 + r0) * K + cc0 * 8;
    const unsigned short* gB1 = B + (size_t)(n0 + r1) * K + cc1 * 8;

    unsigned short* lA0 = &As[(2 * w + 0) * 512];
    unsigned short* lA1 = &As[(2 * w + 1) * 512];
    unsigned short* lB0 = &Bs[(2 * w + 0) * 512];
    unsigned short* lB1 = &Bs[(2 * w + 1) * 512];

    const int rsw = (l16 >> 1) & 3;

    for (int k0 = 0; k0 < K; k0 += 32) {
        __syncthreads();
        GLDS16(gA0 + k0, lA0);
        GLDS16(gA1 + k0, lA1);
        GLDS16(gB0 + k0, lB0);
        GLDS16(gB1 + k0, lB1);
        __syncthreads();

        short8 af[4], bf[4];
#pragma unroll
        for (int t = 0; t < 4; t++) {
            af[t] = *(const short8*)&As[(wm * 64 + t * 16 + l16) * 32 + (quad ^ rsw) * 8];
            bf[t] = *(const short8*)&Bs[(wn * 64 + t * 16 + l16) * 32 + (quad ^ rsw) * 8];
        }
#pragma unroll
        for (int tm = 0; tm < 4; tm++)
#pragma unroll
            for (int tn = 0; tn < 4; tn++)
                acc[tm][tn] = __builtin_amdgcn_mfma_f32_16x16x32_bf16(
                    af[tm], bf[tn], acc[tm][tn], 0, 0, 0);
    }

#pragma unroll
    for (int tm = 0; tm < 4; tm++) {
#pragma unroll
        for (int tn = 0; tn < 4; tn++) {
#pragma unroll
            for (int r = 0; r < 4; r++) {
                int m = m0 + wm * 64 + tm * 16 + quad * 4 + r;
                int n = n0 + wn * 64 + tn * 16 + l16;
                if constexpr (sizeof(OUT) == 4)
                    C[(size_t)m * N + n] = acc[tm][tn][r];
                else
                    C[(size_t)m * N + n] = f2bf(acc[tm][tn][r]);
            }
        }
    }
}

// ---------- fused RoPE split + V transpose, bf16 qkv input ----------
__global__ __launch_bounds__(256)
void ropevt(const unsigned short* __restrict__ qkv,
            unsigned short* __restrict__ qb, unsigned short* __restrict__ kb,
            unsigned short* __restrict__ vtb) {
    __shared__ unsigned short tile[64][72];   // V slice, bf16
    const int tid = threadIdx.x;
    const int bh  = blockIdx.y;
    const int b = bh >> 4, h = bh & 15;
    const int t0 = blockIdx.x * 64;

    // ---- RoPE for q,k: 64 rows x 32 pairs = 2048 pairs, 8 per thread ----
    const float QS = 0.18033688f;   // 0.125 * log2(e)
#pragma unroll
    for (int rep = 0; rep < 8; rep++) {
        int idx  = rep * 256 + tid;
        int p    = idx & 31;
        int trow = idx >> 5;
        int t    = t0 + trow;

        size_t src = (size_t)(b * TT + t) * 3072 + h * 64 + 2 * p;
        ushort2 qu = *(const ushort2*)(qkv + src);
        ushort2 ku = *(const ushort2*)(qkv + src + 1024);
        float qx = bf2f(qu.x), qy = bf2f(qu.y);
        float kx = bf2f(ku.x), ky = bf2f(ku.y);

        float invf = __powf(10000.f, -((float)(2 * p)) / 64.f);
        float ang  = (float)t * invf;
        float sn, cs;
        __sincosf(ang, &sn, &cs);

        size_t dst = ((size_t)bh * TT + t) * 64 + 2 * p;
        ushort2 qo, ko;
        qo.x = f2bf((qx * cs - qy * sn) * QS); qo.y = f2bf((qy * cs + qx * sn) * QS);
        ko.x = f2bf(kx * cs - ky * sn); ko.y = f2bf(ky * cs + kx * sn);
        *(ushort2*)(qb + dst) = qo;
        *(ushort2*)(kb + dst) = ko;
    }

    // ---- V transpose (bf16 in, f16 out, odd-row 8B half-swap) ----
    const int row = tid >> 2;
    const unsigned short* src = qkv + ((size_t)(b * TT) + t0 + row) * 3072 + 2048 + h * 64;
    {
        int cb = (tid & 3) * 16;
        ushort8 v0 = *(const ushort8*)(src + cb);
        ushort8 v1 = *(const ushort8*)(src + cb + 8);
#pragma unroll
        for (int i = 0; i < 8; i++) tile[row][cb + i] = v0[i];
#pragma unroll
        for (int i = 0; i < 8; i++) tile[row][cb + 8 + i] = v1[i];
    }
    __syncthreads();

    const int d  = tid >> 2;
    const int tc = tid & 3;
    const int hs = (d & 1) * 4;
    ushort8 o0, o1;
#pragma unroll
    for (int i = 0; i < 8; i++) {
        _Float16 hv = (_Float16)bf2f(tile[tc * 16 + (i ^ hs)][d]);
        o0[i] = __builtin_bit_cast(unsigned short, hv);
    }
#pragma unroll
    for (int i = 0; i < 8; i++) {
        _Float16 hv = (_Float16)bf2f(tile[tc * 16 + 8 + (i ^ hs)][d]);
        o1[i] = __builtin_bit_cast(unsigned short, hv);
    }
    unsigned short* dst = vtb + ((size_t)bh * 64 + d) * TT + t0 + tc * 16;
    *(ushort8*)(dst) = o0;
    *(ushort8*)(dst + 8) = o1;
}

// ---------- MFMA flash attention (causal): 128 q-rows/block, transposed-S, dbuf LDS ----------
// Wave w owns 32 q-rows (2 groups of 16) sharing one K/V fragment set per tile:
// 32 QK + 32 PV MFMAs per staged tile per wave (2x the old work per barrier).
// Waves whose rows lie entirely below a tile skip it (wave-uniform, causal-exact).
__global__ __launch_bounds__(256, 3)
void attn_mfma(const unsigned short* __restrict__ qb,
               const unsigned short* __restrict__ kb,
               const unsigned short* __restrict__ vtb,
               unsigned short* __restrict__ out) {
    __shared__ unsigned short Ks[2][64 * 64];   // [t][d] bf16, chunk-swizzled
    __shared__ unsigned short Vs[2][64 * 64];   // [d][t] f16,  chunk-swizzled + half-swapped

    const int tid  = threadIdx.x;
    const int lane = tid & 63;
    const int w    = tid >> 6;
    const int quad = lane >> 4;
    const int l16  = lane & 15;

    const int bh = blockIdx.x;                   // head pinned to one XCD (32 % 8)
    // pair long+short row-blocks on the same CU: y -> {15,0,14,1,...}
    const int y   = blockIdx.y;
    const int qb2 = (y & 1) ? (y >> 1) : (15 - (y >> 1));
    const int Q0  = qb2 * 128;

    const unsigned short* Qp = qb + ((size_t)bh * TT + Q0 + w * 32) * 64;
    const unsigned short* Kp = kb + (size_t)bh * TT * 64;
    const unsigned short* Vp = vtb + (size_t)bh * 64 * TT;   // f16 bits in ushort

    // Q fragments, 2 groups of 16 rows: n = l16, k = ks*32 + quad*8 + j
    short8 aq[2][2];
#pragma unroll
    for (int g = 0; g < 2; g++)
#pragma unroll
        for (int ks = 0; ks < 2; ks++)
            aq[g][ks] = *(const short8*)(Qp + (size_t)(g * 16 + l16) * 64 + ks * 32 + quad * 8);

    floatx4 Oacc[2][4];   // O^T per group: row d = dt*16 + quad*4 + r, col q = l16
#pragma unroll
    for (int g = 0; g < 2; g++)
#pragma unroll
        for (int dt = 0; dt < 4; dt++) Oacc[g][dt] = (floatx4){0.f, 0.f, 0.f, 0.f};
    float m[2] = {-1e30f, -1e30f}, l[2] = {0.f, 0.f};

    const int ntiles = 2 * qb2 + 2;
    const int myDiag = 2 * qb2 + (w >> 1);       // last tile this wave actually needs
    const int qloc0  = (w & 1) * 32 + l16;       // q position within the wave's 64-half

#define STAGE(IT, P)                                                                      \
    {                                                                                     \
        const int j0s = (IT) * 64;                                                        \
        _Pragma("unroll")                                                                 \
        for (int rep = 0; rep < 2; rep++) {                                               \
            int c    = rep * 256 + tid;                                                   \
            int row  = c >> 3, sl = c & 7;                                                \
            GLDS16(Kp + (size_t)(j0s + row) * 64 + (sl ^ (row & 7)) * 8, &Ks[P][c * 8]);  \
            GLDS16(Vp + (size_t)row * TT + j0s + (sl ^ ((row >> 1) & 7)) * 8,             \
                   &Vs[P][c * 8]);                                                        \
        }                                                                                 \
    }

    STAGE(0, 0);
    __syncthreads();

    const int ksw = l16 & 7;
    const int vsw = (l16 >> 1) & 7;
    const int vsub = ((quad & 1) ^ (l16 & 1)) * 4;

    for (int it = 0; it < ntiles; ++it) {
        const int p = it & 1;
        if (it + 1 < ntiles) STAGE(it + 1, p ^ 1);

        if (it <= myDiag) {
            // K fragments: shared by both groups (loaded once per tile)
            short8 kf[2][4];
#pragma unroll
            for (int ks = 0; ks < 2; ks++)
#pragma unroll
                for (int nt = 0; nt < 4; nt++)
                    kf[ks][nt] = *(const short8*)&Ks[p][(nt * 16 + l16) * 64 + ((ks * 4 + quad) ^ ksw) * 8];
            // V fragments: shared by both groups
            half4 vf[4][4];
#pragma unroll
            for (int dt = 0; dt < 4; dt++)
#pragma unroll
                for (int nt = 0; nt < 4; nt++) {
                    int c = nt * 2 + (quad >> 1);
                    vf[dt][nt] = *(const half4*)&Vs[p][(dt * 16 + l16) * 64 + (c ^ vsw) * 8 + vsub];
                }

#pragma unroll
            for (int g = 0; g < 2; g++) {
                floatx4 sacc[4];
#pragma unroll
                for (int nt = 0; nt < 4; nt++) sacc[nt] = (floatx4){0.f, 0.f, 0.f, 0.f};
#pragma unroll
                for (int ks = 0; ks < 2; ks++)
#pragma unroll
                    for (int nt = 0; nt < 4; nt++)
                        sacc[nt] = __builtin_amdgcn_mfma_f32_16x16x32_bf16(
                            kf[ks][nt], aq[g][ks], sacc[nt], 0, 0, 0);

                if (it == myDiag) {
                    const int qg = qloc0 + g * 16;   // q within this 64-tile
#pragma unroll
                    for (int nt = 0; nt < 4; nt++)
#pragma unroll
                        for (int r = 0; r < 4; r++)
                            if (nt * 16 + quad * 4 + r > qg) sacc[nt][r] = -1e30f;
                }

                float mx = sacc[0][0];
#pragma unroll
                for (int nt = 0; nt < 4; nt++)
#pragma unroll
                    for (int r = 0; r < 4; r++) mx = fmaxf(mx, sacc[nt][r]);
                mx = fmaxf(mx, __shfl_xor(mx, 16));
                mx = fmaxf(mx, __shfl_xor(mx, 32));
                float mnew  = fmaxf(m[g], mx);
                float alpha = __builtin_amdgcn_exp2f(m[g] - mnew);
                m[g] = mnew;
                float psum = 0.f;
#pragma unroll
                for (int nt = 0; nt < 4; nt++)
#pragma unroll
                    for (int r = 0; r < 4; r++) {
                        float pv = __builtin_amdgcn_exp2f(sacc[nt][r] - mnew);
                        sacc[nt][r] = pv;
                        psum += pv;
                    }
                psum += __shfl_xor(psum, 16);
                psum += __shfl_xor(psum, 32);
                l[g] = l[g] * alpha + psum;

#pragma unroll
                for (int dt = 0; dt < 4; dt++)
#pragma unroll
                    for (int r = 0; r < 4; r++) Oacc[g][dt][r] *= alpha;

                half4 bp[4];
#pragma unroll
                for (int nt = 0; nt < 4; nt++) {
                    half4 h;
                    h[0] = (_Float16)sacc[nt][0];
                    h[1] = (_Float16)sacc[nt][1];
                    h[2] = (_Float16)sacc[nt][2];
                    h[3] = (_Float16)sacc[nt][3];
                    bp[nt] = h;
                }

#pragma unroll
                for (int dt = 0; dt < 4; dt++)
#pragma unroll
                    for (int nt = 0; nt < 4; nt++)
                        Oacc[g][dt] = MFMA_PV(vf[dt][nt], bp[nt], Oacc[g][dt]);
            }
        }

        __syncthreads();   // drains stage(it+1); protects buffers
    }
#undef STAGE

    // epilogue
    const int b = bh >> 4, h = bh & 15;
#pragma unroll
    for (int g = 0; g < 2; g++) {
        const float inv = 1.f / l[g];
        const size_t base = ((size_t)(b * TT + Q0 + w * 32 + g * 16 + l16)) * DMODEL + h * 64 + quad * 4;
#pragma unroll
        for (int dt = 0; dt < 4; dt++) {
            ushort4 pk;
            pk.x = f2bf(Oacc[g][dt][0] * inv);
            pk.y = f2bf(Oacc[g][dt][1] * inv);
            pk.z = f2bf(Oacc[g][dt][2] * inv);
            pk.w = f2bf(Oacc[g][dt][3] * inv);
            *(ushort4*)(out + base + dt * 16) = pk;
        }
    }
}

// ---------- launch ----------
extern "C" void kernel_launch(void* const* d_in, const int* in_sizes, int n_in,
                              void* d_out, int out_size, void* d_ws, size_t ws_size,
                              hipStream_t stream) {
    const float* x     = (const float*)d_in[0];   // [2,2048,1024]
    const float* w_qkv = (const float*)d_in[1];   // [3072,1024]
    const float* w_out = (const float*)d_in[2];   // [1024,1024]
    float* out = (float*)d_out;                   // [2,2048,1024]

    char* ws = (char*)d_ws;

    unsigned short* xb   = (unsigned short*)(ws);                 // 8 MB
    unsigned short* wqb  = (unsigned short*)(ws + 8388608);       // 6 MB
    unsigned short* wob  = (unsigned short*)(ws + 14680064);      // 2 MB
    unsigned short* qkvb = (unsigned short*)(ws + 16777216);      // 24 MB (bf16)
    unsigned short* qb   = (unsigned short*)(ws + 41943040);      // 8 MB
    unsigned short* kb   = (unsigned short*)(ws + 50331648);      // 8 MB
    unsigned short* vtb  = (unsigned short*)(ws + 58720256);      // 8 MB (f16)
    unsigned short* attb = (unsigned short*)(ws + 67108864);      // 8 MB

    castk3<<<8192, 256, 0, stream>>>(x, xb, w_qkv, wqb, w_out, wob);

    // qkv = x @ w_qkv^T   (M=4096, N=3072, K=1024), bf16 output
    gemm_bt<unsigned short><<<dim3(3072 / 128, 4096 / 128), 256, 0, stream>>>(
        xb, wqb, qkvb, 4096, 3072, 1024);

    // fused rope + v-transpose (bf16 input)
    ropevt<<<dim3(TT / 64, BB * NHEADS), 256, 0, stream>>>(qkvb, qb, kb, vtb);

    // grid: x = bh (XCD locality), y = 16 row-blocks of 128 (paired lengths)
    attn_mfma<<<dim3(BB * NHEADS, TT / 128), 256, 0, stream>>>(qb, kb, vtb, attb);

    // out = attn @ w_out^T (M=4096, N=1024, K=1024), fp32 output
    gemm_bt<float><<<dim3(1024 / 128, 4096 / 128), 256, 0, stream>>>(
        attb, wob, out, 4096, 1024, 1024);
}